// Round 14
// baseline (130.316 us; speedup 1.0000x reference)
//
#include <hip/hip_runtime.h>
#include <hip/hip_fp16.h>
#include <stdint.h>

// Problem constants (fixed by the reference)
#define Bn 2
#define Qn 2048
#define Kn 2048
#define Hn 16
#define Dn 64
#define Rn 32

#define LOG2E_8 0.18033688011112042f   // 0.125 * log2(e)
#define MASK_NEG -14426.950408889634f  // -10000 * log2(e)

typedef __attribute__((ext_vector_type(8))) short short8v;   // 8 bf16 (4 VGPR) MFMA operand
typedef __attribute__((ext_vector_type(4))) float f32x4;     // MFMA accumulator
typedef __attribute__((ext_vector_type(4))) uint32_t u32x4;

static __device__ __forceinline__ uint16_t bf16rn(float f) {
  uint32_t u = __builtin_bit_cast(uint32_t, f);
  u += 0x7FFFu + ((u >> 16) & 1u);          // round-to-nearest-even
  return (uint16_t)(u >> 16);
}
static __device__ __forceinline__ float bf16f(uint16_t h) {
  return __builtin_bit_cast(float, (uint32_t)h << 16);
}
static __device__ __forceinline__ float exp2a(float x) {
  float r; asm("v_exp_f32 %0, %1" : "=v"(r) : "v"(x)); return r;
}
static __device__ __forceinline__ uint32_t cvtpk(float lo, float hi) {
  uint32_t r; asm("v_cvt_pk_bf16_f32 %0, %1, %2" : "=v"(r) : "v"(lo), "v"(hi)); return r;
}
static __device__ __forceinline__ void gl_lds16(const void* g, void* l) {
  __builtin_amdgcn_global_load_lds((const __attribute__((address_space(1))) void*)g,
                                   (__attribute__((address_space(3))) void*)l, 16, 0, 0);
}

// ---------------- pre-pass 1: pack (rel_id | mask<<5) into one byte (6-bit table idx) ----
__global__ void pack_kernel(const int* __restrict__ ids,
                            const int* __restrict__ msk,
                            uint32_t* __restrict__ outp, int n4) {
  int i = blockIdx.x * 256 + threadIdx.x;
  if (i >= n4) return;
  int4 a = reinterpret_cast<const int4*>(ids)[i];
  int4 m = reinterpret_cast<const int4*>(msk)[i];
  uint32_t v = (uint32_t)((a.x | (m.x << 5)) & 0x3f)
             | ((uint32_t)((a.y | (m.y << 5)) & 0x3f) << 8)
             | ((uint32_t)((a.z | (m.z << 5)) & 0x3f) << 16)
             | ((uint32_t)((a.w | (m.w << 5)) & 0x3f) << 24);
  outp[i] = v;
}

// ---------------- pre-pass 2: K (single bf16, pre-scaled by LOG2E_8) + V (bf16) ----------
__global__ __launch_bounds__(256) void kfrag6_kernel(const float* __restrict__ Kg,
                                                     const float* __restrict__ Vg,
                                                     uint8_t* __restrict__ frag) {
  const int bid = blockIdx.x;
  const int c = bid & 63;
  const int h = (bid >> 6) & 15;
  const int b = bid >> 10;
  uint8_t* panel = frag + (size_t)(b * 16 + h) * 524288u + (size_t)c * 8192u;
  uint4* kf = reinterpret_cast<uint4*>(panel);
  uint4* vf = reinterpret_cast<uint4*>(panel + 4096);
  const int tid = threadIdx.x;
  const int sdq = tid & 7, srow = (tid >> 3) & 15, stile = tid >> 7;
  const int sg = sdq & 3, sdm = sdq >> 2;
  const float* kp = Kg + ((((size_t)b * Kn) + c * 32 + stile * 16 + srow) * Hn + h) * Dn + (sdm * 32 + sg * 4);
  const float4 x0 = *reinterpret_cast<const float4*>(kp);
  const float4 x1 = *reinterpret_cast<const float4*>(kp + 16);
  const float xs0[4] = {x0.x * LOG2E_8, x0.y * LOG2E_8, x0.z * LOG2E_8, x0.w * LOG2E_8};
  const float xs1[4] = {x1.x * LOG2E_8, x1.y * LOG2E_8, x1.z * LOG2E_8, x1.w * LOG2E_8};
  uint4 uh;
  uh.x = bf16rn(xs0[0]) | ((uint32_t)bf16rn(xs0[1]) << 16);
  uh.y = bf16rn(xs0[2]) | ((uint32_t)bf16rn(xs0[3]) << 16);
  uh.z = bf16rn(xs1[0]) | ((uint32_t)bf16rn(xs1[1]) << 16);
  uh.w = bf16rn(xs1[2]) | ((uint32_t)bf16rn(xs1[3]) << 16);
  kf[(stile * 2 + sdm) * 64 + (srow + 16 * sg)] = uh;
  const int vd = tid & 63, vkq = tid >> 6;
  const float* vp = Vg + ((((size_t)b * Kn) + c * 32 + vkq * 4) * Hn + h) * Dn + vd;
  float v0[4], v1[4];
#pragma unroll
  for (int i = 0; i < 4; ++i) {
    v0[i] = vp[i * (Hn * Dn)];
    v1[i] = vp[(16 + i) * (Hn * Dn)];
  }
  uint4 uv;
  uv.x = bf16rn(v0[0]) | ((uint32_t)bf16rn(v0[1]) << 16);
  uv.y = bf16rn(v0[2]) | ((uint32_t)bf16rn(v0[3]) << 16);
  uv.z = bf16rn(v1[0]) | ((uint32_t)bf16rn(v1[1]) << 16);
  uv.w = bf16rn(v1[2]) | ((uint32_t)bf16rn(v1[3]) << 16);
  vf[(vd >> 4) * 64 + (vd & 15) + 16 * vkq] = uv;
}

// ---------------- pre-pass 3: f16 score table via MFMA (hi/lo E and Q; R11-verified) ----
__global__ __launch_bounds__(256) void tab2_kernel(const float* __restrict__ Qg,
                                                   const float* __restrict__ Eg,
                                                   const float* __restrict__ biasg,
                                                   __half* __restrict__ tabg) {
  const int tid = threadIdx.x;
  const int lane = tid & 63;
  const int w = tid >> 6;
  const int qr = lane & 15;
  const int g = lane >> 4;
  const int bid = blockIdx.x;
  const int qt = bid & 31;
  const int h = (bid >> 5) & 15;
  const int b = bid >> 9;
  const int q0 = qt * 64 + w * 16;

  short8v eh[2][2], el[2][2];
#pragma unroll
  for (int rt = 0; rt < 2; ++rt)
#pragma unroll
    for (int dm = 0; dm < 2; ++dm) {
      const float* ep = Eg + (((size_t)(rt * 16 + qr) * Hn + h) * Dn) + dm * 32 + 4 * g;
      const float4 x0 = *reinterpret_cast<const float4*>(ep);
      const float4 x1 = *reinterpret_cast<const float4*>(ep + 16);
      const float xs[8] = {x0.x * LOG2E_8, x0.y * LOG2E_8, x0.z * LOG2E_8, x0.w * LOG2E_8,
                           x1.x * LOG2E_8, x1.y * LOG2E_8, x1.z * LOG2E_8, x1.w * LOG2E_8};
#pragma unroll
      for (int j = 0; j < 8; ++j) {
        const uint16_t hi = bf16rn(xs[j]);
        eh[rt][dm][j] = (short)hi;
        el[rt][dm][j] = (short)bf16rn(xs[j] - bf16f(hi));
      }
    }
  short8v qh[2], ql[2];
#pragma unroll
  for (int dm = 0; dm < 2; ++dm) {
    const float* qp = Qg + (((size_t)b * Qn + q0 + qr) * Hn + h) * Dn + dm * 32 + 4 * g;
    const float4 x0 = *reinterpret_cast<const float4*>(qp);
    const float4 x1 = *reinterpret_cast<const float4*>(qp + 16);
    const float xs[8] = {x0.x, x0.y, x0.z, x0.w, x1.x, x1.y, x1.z, x1.w};
#pragma unroll
    for (int j = 0; j < 8; ++j) {
      const uint16_t hi = bf16rn(xs[j]);
      qh[dm][j] = (short)hi;
      ql[dm][j] = (short)bf16rn(xs[j] - bf16f(hi));
    }
  }
#pragma unroll
  for (int rt = 0; rt < 2; ++rt) {
    f32x4 d;
#pragma unroll
    for (int j = 0; j < 4; ++j)
      d[j] = LOG2E_8 * biasg[(rt * 16 + 4 * g + j) * Hn + h];
#pragma unroll
    for (int dm = 0; dm < 2; ++dm) {
      d = __builtin_amdgcn_mfma_f32_16x16x32_bf16(eh[rt][dm], qh[dm], d, 0, 0, 0);
      d = __builtin_amdgcn_mfma_f32_16x16x32_bf16(el[rt][dm], qh[dm], d, 0, 0, 0);
      d = __builtin_amdgcn_mfma_f32_16x16x32_bf16(eh[rt][dm], ql[dm], d, 0, 0, 0);
    }
    const size_t rowo = ((size_t)(b * 16 + h) * 2048 + q0 + qr) * 64;
    union { ushort4 u4; __half hh[4]; } um, uu;
#pragma unroll
    for (int j = 0; j < 4; ++j) {
      um.hh[j] = __float2half(d[j] + MASK_NEG);
      uu.hh[j] = __float2half(d[j]);
    }
    *reinterpret_cast<ushort4*>(&tabg[rowo + rt * 16 + 4 * g]) = um.u4;
    *reinterpret_cast<ushort4*>(&tabg[rowo + 32 + rt * 16 + 4 * g]) = uu.u4;
  }
}

// ---------------- attn10: no LDS staging, no loop barriers; frags direct from global -----
// GRID = Bn*Hn*(Qn/64) = 1024 blocks (block covers 64 q x ALL keys; split-K is IN-BLOCK).
// 256-thread blocks, 4 waves: wave w = (ks = w>>1, wq = w&1).
// K/V fragments are lane-linear in the panel -> global_load_dwordx4 straight to VGPRs.
// LDS holds only the 8 KB tab (random gather) + epilogue merge buffer.
__global__ __launch_bounds__(256, 3) void attn10_kernel(
    const float* __restrict__ Qg, const uint8_t* __restrict__ packed,
    const uint8_t* __restrict__ kfragp, const __half* __restrict__ tabg,
    float* __restrict__ outg) {
  // LDS: [0,8192) tab f16[64 q][64]; [8192,24576) acc1 f32[64][64]; [24576,24832) l1 f32[64]
  __shared__ alignas(16) char smem[24832];
  const int tid = threadIdx.x;
  const int lane = tid & 63;
  const int w = tid >> 6;      // 0..3
  const int wq = w & 1;
  const int ks = w >> 1;
  const int qr = lane & 15;
  const int g = lane >> 4;

  // XCD-aware swizzle (1024 blocks = 8 XCDs x 128) — bijective
  const int wi = (blockIdx.x & 7) * 128 + (blockIdx.x >> 3);
  const int qt = wi & 31;      // 32 q-tiles
  const int h = (wi >> 5) & 15;
  const int b = wi >> 9;       // in [0,2)
  const int q0 = qt * 64;

  // ---- stage tab rows [q0,q0+64) (8 KB linear, 2 gl_lds per wave) ----
  {
    const uint8_t* tsrc = reinterpret_cast<const uint8_t*>(
        tabg + ((size_t)(b * 16 + h) * 2048 + q0) * 64);
    char* ld = smem + w * 2048;
    gl_lds16(tsrc + (size_t)w * 2048 + (size_t)lane * 16, ld);
    gl_lds16(tsrc + (size_t)w * 2048 + 1024 + (size_t)lane * 16, ld + 1024);
  }

  const uint8_t* panel = kfragp + (size_t)(b * 16 + h) * 524288u + (size_t)(ks * 32) * 8192u +
                         (size_t)lane * 16;

  // ---- Q fragments direct from global (bf16 via cvtpk; R8-verified mapping) ----
  short8v qhi[2][2];
#pragma unroll
  for (int t = 0; t < 2; ++t)
#pragma unroll
    for (int dm = 0; dm < 2; ++dm) {
      const float* qp = Qg + (((size_t)b * Qn + q0 + wq * 32 + t * 16 + qr) * Hn + h) * Dn +
                        dm * 32 + 4 * g;
      const float4 x0 = *reinterpret_cast<const float4*>(qp);
      const float4 x1 = *reinterpret_cast<const float4*>(qp + 16);
      u32x4 u;
      u[0] = cvtpk(x0.x, x0.y); u[1] = cvtpk(x0.z, x0.w);
      u[2] = cvtpk(x1.x, x1.y); u[3] = cvtpk(x1.z, x1.w);
      qhi[t][dm] = __builtin_bit_cast(short8v, u);
    }

  // ---- packed-byte and table row bases ----
  int64_t prow[2];
  int trow[2];
#pragma unroll
  for (int t = 0; t < 2; ++t) {
    prow[t] = ((int64_t)(b * Qn + q0 + wq * 32 + t * 16 + qr)) * Kn + ks * 1024 + 4 * g;
    trow[t] = (wq * 32 + t * 16 + qr) * 64;
  }
  uint32_t pc[2][2], pn[2][2] = {{0u, 0u}, {0u, 0u}};
#pragma unroll
  for (int t = 0; t < 2; ++t)
#pragma unroll
    for (int st = 0; st < 2; ++st)
      pc[t][st] = *reinterpret_cast<const uint32_t*>(packed + prow[t] + st * 16);

  // ---- K frags for chunk 0 (registers) ----
  short8v kc[4], kn[4];
#pragma unroll
  for (int s = 0; s < 4; ++s)
    kc[s] = *reinterpret_cast<const short8v*>(panel + s * 1024);

  // tab staged? drain gl_lds before gathers (once)
  asm volatile("s_waitcnt vmcnt(0)" ::: "memory");
  __builtin_amdgcn_sched_barrier(0);
  __syncthreads();

  const short8v ones = {(short)0x3F80, (short)0x3F80, (short)0x3F80, (short)0x3F80,
                        (short)0x3F80, (short)0x3F80, (short)0x3F80, (short)0x3F80};
  const __half* tabh = reinterpret_cast<const __half*>(smem);

  f32x4 acc[2][4] = {{{0.f,0.f,0.f,0.f},{0.f,0.f,0.f,0.f},{0.f,0.f,0.f,0.f},{0.f,0.f,0.f,0.f}},
                     {{0.f,0.f,0.f,0.f},{0.f,0.f,0.f,0.f},{0.f,0.f,0.f,0.f},{0.f,0.f,0.f,0.f}}};
  f32x4 accl[2] = {{0.f,0.f,0.f,0.f},{0.f,0.f,0.f,0.f}};

  for (int c = 0; c < 32; ++c) {
    // prefetch next chunk's K frags + packed bytes into registers (one-iter lead)
    if (c + 1 < 32) {
      const uint8_t* pnx = panel + (size_t)(c + 1) * 8192u;
#pragma unroll
      for (int s = 0; s < 4; ++s)
        kn[s] = *reinterpret_cast<const short8v*>(pnx + s * 1024);
      const int64_t kb = (int64_t)(c + 1) * 32;
#pragma unroll
      for (int t = 0; t < 2; ++t)
#pragma unroll
        for (int st = 0; st < 2; ++st)
          pn[t][st] = *reinterpret_cast<const uint32_t*>(packed + prow[t] + kb + st * 16);
    }
    // V frags for this chunk (used after QK + softmax -> latency covered)
    short8v vv[4];
    {
      const uint8_t* pv4 = panel + (size_t)c * 8192u + 4096;
#pragma unroll
      for (int dt = 0; dt < 4; ++dt)
        vv[dt] = *reinterpret_cast<const short8v*>(pv4 + dt * 1024);
    }

    // ---- QK^T (swapped, single bf16 pre-scaled) on kc ----
    f32x4 s[2][2] = {{{0.f,0.f,0.f,0.f},{0.f,0.f,0.f,0.f}},
                     {{0.f,0.f,0.f,0.f},{0.f,0.f,0.f,0.f}}};
    __builtin_amdgcn_s_setprio(1);
#pragma unroll
    for (int dm = 0; dm < 2; ++dm) {
      const short8v k0 = kc[dm];
      const short8v k1 = kc[2 + dm];
#pragma unroll
      for (int t = 0; t < 2; ++t) {
        s[t][0] = __builtin_amdgcn_mfma_f32_16x16x32_bf16(k0, qhi[t][dm], s[t][0], 0, 0, 0);
        s[t][1] = __builtin_amdgcn_mfma_f32_16x16x32_bf16(k1, qhi[t][dm], s[t][1], 0, 0, 0);
      }
    }
    __builtin_amdgcn_s_setprio(0);

    // ---- per-tile: tab gather + raw exp2 + PV + ones-MFMA row-sum ----
#pragma unroll
    for (int t = 0; t < 2; ++t) {
      float pv[8];
#pragma unroll
      for (int i = 0; i < 8; ++i) {
        const int st = i >> 2, r = i & 3;
        const uint32_t v = (pc[t][st] >> (8 * r)) & 63u;
        pv[i] = exp2a(s[t][st][r] + __half2float(tabh[trow[t] + (int)v]));
      }
      u32x4 pu;
      pu[0] = cvtpk(pv[0], pv[1]); pu[1] = cvtpk(pv[2], pv[3]);
      pu[2] = cvtpk(pv[4], pv[5]); pu[3] = cvtpk(pv[6], pv[7]);
      const short8v pa = __builtin_bit_cast(short8v, pu);
      __builtin_amdgcn_s_setprio(1);
#pragma unroll
      for (int dt = 0; dt < 4; ++dt)
        acc[t][dt] = __builtin_amdgcn_mfma_f32_16x16x32_bf16(pa, vv[dt], acc[t][dt], 0, 0, 0);
      accl[t] = __builtin_amdgcn_mfma_f32_16x16x32_bf16(pa, ones, accl[t], 0, 0, 0);
      __builtin_amdgcn_s_setprio(0);
    }

#pragma unroll
    for (int s4i = 0; s4i < 4; ++s4i) kc[s4i] = kn[s4i];
#pragma unroll
    for (int t = 0; t < 2; ++t) { pc[t][0] = pn[t][0]; pc[t][1] = pn[t][1]; }
  }

  // ---- epilogue: in-block merge (ks=1 partials -> LDS; barrier; ks=0 combines) ----
  float* const acc1s = reinterpret_cast<float*>(smem + 8192);   // [64][64]
  float* const l1s   = reinterpret_cast<float*>(smem + 24576);  // [64]
  if (ks == 1) {
#pragma unroll
    for (int t = 0; t < 2; ++t) {
#pragma unroll
      for (int dt = 0; dt < 4; ++dt)
#pragma unroll
        for (int r = 0; r < 4; ++r)
          acc1s[(wq * 32 + t * 16 + 4 * g + r) * 64 + dt * 16 + qr] = acc[t][dt][r];
#pragma unroll
      for (int r = 0; r < 4; ++r)
        l1s[wq * 32 + t * 16 + 4 * g + r] = accl[t][r];  // same value across qr lanes
    }
  }
  __syncthreads();
  if (ks == 0) {
#pragma unroll
    for (int t = 0; t < 2; ++t) {
      const f32x4 l1v = *reinterpret_cast<const f32x4*>(&l1s[wq * 32 + t * 16 + 4 * g]);
      f32x4 linv;
#pragma unroll
      for (int r = 0; r < 4; ++r) linv[r] = 1.0f / (accl[t][r] + l1v[r]);
#pragma unroll
      for (int dt = 0; dt < 4; ++dt)
#pragma unroll
        for (int r = 0; r < 4; ++r) {
          const int lrow = wq * 32 + t * 16 + 4 * g + r;
          const float o = (acc[t][dt][r] + acc1s[lrow * 64 + dt * 16 + qr]) * linv[r];
          outg[(((size_t)b * Qn + q0 + lrow) * Hn + h) * Dn + dt * 16 + qr] = o;
        }
    }
  }
}

// ---------------- fallback (ws too small): fully self-contained, no scratch ----------------
__global__ __launch_bounds__(256) void attn_old_kernel(
    const float* __restrict__ Qg, const float* __restrict__ Kg,
    const float* __restrict__ Vg, const int* __restrict__ maskg,
    const int* __restrict__ idsg, const float* __restrict__ Eg,
    const float* __restrict__ biasg, float* __restrict__ outg) {
  __shared__ alignas(16) char smem[34304];
  float* const allrel = reinterpret_cast<float*>(smem);
  float* const q_lds  = reinterpret_cast<float*>(smem + 8448);
  float* const et_lds = reinterpret_cast<float*>(smem + 25856);
  uint4* const kfrag  = reinterpret_cast<uint4*>(smem + 8448);
  uint4* const vfrag  = reinterpret_cast<uint4*>(smem + 16640);

  const int tid  = threadIdx.x;
  const int lane = tid & 63;
  const int w    = tid >> 6;
  const int qr   = lane & 15;
  const int g    = lane >> 4;

  const int bid = blockIdx.x;
  const int h  = bid & 15;
  const int qt = (bid >> 4) & 31;
  const int b  = bid >> 9;
  const int q0 = qt * 64;

  {
    const int row = tid >> 2, dq = (tid & 3) * 16;
    const float4* s4 =
        reinterpret_cast<const float4*>(Qg + (((b * Qn) + q0 + row) * Hn + h) * Dn + dq);
    float4* dst = reinterpret_cast<float4*>(&q_lds[row * 68 + dq]);
#pragma unroll
    for (int i = 0; i < 4; ++i) dst[i] = s4[i];
  }
  {
    const int r = tid >> 3, d0 = (tid & 7) * 8;
    const float* src = Eg + ((r * Hn + h) * Dn + d0);
#pragma unroll
    for (int i = 0; i < 8; ++i) et_lds[(d0 + i) * 33 + r] = src[i];
  }
  __syncthreads();

  const int qloc = w * 16 + qr;
  short8v qhi[2], qlo[2];
#pragma unroll
  for (int dm = 0; dm < 2; ++dm) {
#pragma unroll
    for (int j = 0; j < 8; ++j) {
      const int dl = (j < 4) ? (4 * g + j) : (16 + 4 * g + (j - 4));
      const float x = q_lds[qloc * 68 + dm * 32 + dl];
      const uint16_t hi = bf16rn(x);
      qhi[dm][j] = (short)hi;
      qlo[dm][j] = (short)bf16rn(x - bf16f(hi));
    }
  }

  {
    const int r = tid & 31, q8 = tid >> 5;
    float acc[8] = {0.f, 0.f, 0.f, 0.f, 0.f, 0.f, 0.f, 0.f};
    const float bias = biasg[r * Hn + h];
    for (int d = 0; d < 64; ++d) {
      const float e = et_lds[d * 33 + r];
#pragma unroll
      for (int i = 0; i < 8; ++i) acc[i] += e * q_lds[(q8 * 8 + i) * 68 + d];
    }
#pragma unroll
    for (int i = 0; i < 8; ++i)
      allrel[(q8 * 8 + i) * 33 + r] = 0.125f * (acc[i] + bias);
  }
  __syncthreads();

  const int sdq = tid & 7, srow = (tid >> 3) & 15, stile = tid >> 7;
  const int sg = sdq & 3, sdm = sdq >> 2;
  int koff = (((b * Kn) + stile * 16 + srow) * Hn + h) * Dn + (sdm * 32 + sg * 4);
  const int kslotH = (stile * 2 + sdm) * 64 + (srow + 16 * sg);
  const int kslotL = (4 + stile * 2 + sdm) * 64 + (srow + 16 * sg);
  const int vd = tid & 63, vkq = tid >> 6;
  int voff = (((b * Kn) + vkq * 4) * Hn + h) * Dn + vd;
  const int vslot = (vd >> 4) * 64 + (vd & 15) + 16 * vkq;

  const int qglob = q0 + qloc;
  const int prow = (b * Qn + qglob) * Kn + 4 * g;

  f32x4 acc[4] = {{0.f,0.f,0.f,0.f},{0.f,0.f,0.f,0.f},{0.f,0.f,0.f,0.f},{0.f,0.f,0.f,0.f}};
  float mrun = -1e30f, lrun = 0.f;

  const short8v* kfs = reinterpret_cast<const short8v*>(kfrag);
  const short8v* vfs = reinterpret_cast<const short8v*>(vfrag);

  for (int c = 0; c < 64; ++c) {
    const int kb = c * 32;
    __syncthreads();
    {
      const float4 x0 = *reinterpret_cast<const float4*>(Kg + koff);
      const float4 x1 = *reinterpret_cast<const float4*>(Kg + koff + 16);
      koff += 32 * Hn * Dn;
      const float xs0[4] = {x0.x, x0.y, x0.z, x0.w};
      const float xs1[4] = {x1.x, x1.y, x1.z, x1.w};
      uint16_t hh[8], ll[8];
#pragma unroll
      for (int i = 0; i < 4; ++i) {
        const uint16_t h0 = bf16rn(xs0[i]);
        const uint16_t h1 = bf16rn(xs1[i]);
        hh[i] = h0; hh[4 + i] = h1;
        ll[i] = bf16rn(xs0[i] - bf16f(h0));
        ll[4 + i] = bf16rn(xs1[i] - bf16f(h1));
      }
      uint4 uh, ul;
      uh.x = hh[0] | ((uint32_t)hh[1] << 16); uh.y = hh[2] | ((uint32_t)hh[3] << 16);
      uh.z = hh[4] | ((uint32_t)hh[5] << 16); uh.w = hh[6] | ((uint32_t)hh[7] << 16);
      ul.x = ll[0] | ((uint32_t)ll[1] << 16); ul.y = ll[2] | ((uint32_t)ll[3] << 16);
      ul.z = ll[4] | ((uint32_t)ll[5] << 16); ul.w = ll[6] | ((uint32_t)ll[7] << 16);
      kfrag[kslotH] = uh;
      kfrag[kslotL] = ul;
    }
    {
      float v0[4], v1[4];
#pragma unroll
      for (int i = 0; i < 4; ++i) {
        v0[i] = Vg[voff + i * (Hn * Dn)];
        v1[i] = Vg[voff + 16 * Hn * Dn + i * (Hn * Dn)];
      }
      voff += 32 * Hn * Dn;
      uint4 uv;
      uv.x = bf16rn(v0[0]) | ((uint32_t)bf16rn(v0[1]) << 16);
      uv.y = bf16rn(v0[2]) | ((uint32_t)bf16rn(v0[3]) << 16);
      uv.z = bf16rn(v1[0]) | ((uint32_t)bf16rn(v1[1]) << 16);
      uv.w = bf16rn(v1[2]) | ((uint32_t)bf16rn(v1[3]) << 16);
      vfrag[vslot] = uv;
    }
    __syncthreads();

    f32x4 s0 = {0.f, 0.f, 0.f, 0.f}, s1 = {0.f, 0.f, 0.f, 0.f};
#pragma unroll
    for (int dm = 0; dm < 2; ++dm) {
      const short8v k0h = kfs[(dm) * 64 + lane];
      const short8v k1h = kfs[(2 + dm) * 64 + lane];
      const short8v k0l = kfs[(4 + dm) * 64 + lane];
      const short8v k1l = kfs[(6 + dm) * 64 + lane];
      s0 = __builtin_amdgcn_mfma_f32_16x16x32_bf16(k0h, qhi[dm], s0, 0, 0, 0);
      s1 = __builtin_amdgcn_mfma_f32_16x16x32_bf16(k1h, qhi[dm], s1, 0, 0, 0);
      s0 = __builtin_amdgcn_mfma_f32_16x16x32_bf16(k0h, qlo[dm], s0, 0, 0, 0);
      s1 = __builtin_amdgcn_mfma_f32_16x16x32_bf16(k1h, qlo[dm], s1, 0, 0, 0);
      s0 = __builtin_amdgcn_mfma_f32_16x16x32_bf16(k0l, qhi[dm], s0, 0, 0, 0);
      s1 = __builtin_amdgcn_mfma_f32_16x16x32_bf16(k1l, qhi[dm], s1, 0, 0, 0);
    }

    float sv[8];
    {
      const int ib = prow + kb;
      const int4 i0 = *reinterpret_cast<const int4*>(idsg + ib);
      const int4 i1 = *reinterpret_cast<const int4*>(idsg + ib + 16);
      const int4 m0 = *reinterpret_cast<const int4*>(maskg + ib);
      const int4 m1 = *reinterpret_cast<const int4*>(maskg + ib + 16);
      const int ia0[4] = {i0.x, i0.y, i0.z, i0.w};
      const int ia1[4] = {i1.x, i1.y, i1.z, i1.w};
      const int ma0[4] = {m0.x, m0.y, m0.z, m0.w};
      const int ma1[4] = {m1.x, m1.y, m1.z, m1.w};
#pragma unroll
      for (int r = 0; r < 4; ++r) {
        sv[r]     = 0.125f * s0[r] + allrel[qloc * 33 + ia0[r]] + (ma0[r] ? 0.f : -10000.f);
        sv[4 + r] = 0.125f * s1[r] + allrel[qloc * 33 + ia1[r]] + (ma1[r] ? 0.f : -10000.f);
      }
    }

    float m8 = sv[0];
#pragma unroll
    for (int i = 1; i < 8; ++i) m8 = fmaxf(m8, sv[i]);
    m8 = fmaxf(m8, __shfl_xor(m8, 16));
    m8 = fmaxf(m8, __shfl_xor(m8, 32));
    const float mnew = fmaxf(mrun, m8);
    const float sc = __expf(mrun - mnew);
    mrun = mnew;
    float pv[8];
    float ps = 0.f;
#pragma unroll
    for (int i = 0; i < 8; ++i) { pv[i] = __expf(sv[i] - mnew); ps += pv[i]; }
    ps += __shfl_xor(ps, 16);
    ps += __shfl_xor(ps, 32);
    lrun = lrun * sc + ps;

    f32x4 scv;
#pragma unroll
    for (int r = 0; r < 4; ++r) scv[r] = __shfl(sc, 4 * g + r);
#pragma unroll
    for (int dt = 0; dt < 4; ++dt) acc[dt] *= scv;

    short8v pa;
#pragma unroll
    for (int i = 0; i < 8; ++i) pa[i] = (short)bf16rn(pv[i]);
#pragma unroll
    for (int dt = 0; dt < 4; ++dt)
      acc[dt] = __builtin_amdgcn_mfma_f32_16x16x32_bf16(pa, vfs[dt * 64 + lane], acc[dt], 0, 0, 0);
  }

  const float linv = 1.0f / lrun;
  f32x4 lv;
#pragma unroll
  for (int r = 0; r < 4; ++r) lv[r] = __shfl(linv, 4 * g + r);
#pragma unroll
  for (int dt = 0; dt < 4; ++dt) {
#pragma unroll
    for (int r = 0; r < 4; ++r) {
      const int qrow = q0 + w * 16 + 4 * g + r;
      outg[(((b * Qn) + qrow) * Hn + h) * Dn + dt * 16 + qr] = acc[dt][r] * lv[r];
    }
  }
}

extern "C" void kernel_launch(void* const* d_in, const int* in_sizes, int n_in,
                              void* d_out, int out_size, void* d_ws, size_t ws_size,
                              hipStream_t stream) {
  const float* Qg    = (const float*)d_in[0];
  const float* Kg    = (const float*)d_in[1];
  const float* Vg    = (const float*)d_in[2];
  const int*   maskg = (const int*)d_in[3];
  const int*   idsg  = (const int*)d_in[4];
  const float* Eg    = (const float*)d_in[5];
  const float* biasg = (const float*)d_in[6];
  float* outg = (float*)d_out;

  // ws layout
  const size_t oPack = 0;                  // 8,388,608
  const size_t oK    = 8388608;            // +16,777,216 -> 25,165,824
  const size_t oT    = 25165824;           // +8,388,608  -> 33,554,432
  const size_t need10 = 33554432;
  const int n4 = (Bn * Qn * Kn) / 4;

  uint8_t* ws = (uint8_t*)d_ws;

  if (ws_size >= need10) {
    pack_kernel<<<n4 / 256, 256, 0, stream>>>(idsg, maskg, (uint32_t*)(ws + oPack), n4);
    kfrag6_kernel<<<Bn * Hn * 64, 256, 0, stream>>>(Kg, Vg, ws + oK);
    tab2_kernel<<<Bn * Hn * 32, 256, 0, stream>>>(Qg, Eg, biasg, (__half*)(ws + oT));
    attn10_kernel<<<Bn * Hn * (Qn / 64), 256, 0, stream>>>(
        Qg, ws + oPack, ws + oK, (const __half*)(ws + oT), outg);
  } else {
    attn_old_kernel<<<Bn * Hn * (Qn / 64), 256, 0, stream>>>(
        Qg, Kg, Vg, maskg, idsg, Eg, biasg, outg);
  }
}

// Round 15
// 107.191 us; speedup vs baseline: 1.2157x; 1.2157x over previous
//
#include <hip/hip_runtime.h>
#include <hip/hip_fp16.h>
#include <stdint.h>

// Problem constants (fixed by the reference)
#define Bn 2
#define Qn 2048
#define Kn 2048
#define Hn 16
#define Dn 64
#define Rn 32

#define LOG2E_8 0.18033688011112042f   // 0.125 * log2(e)
#define MASK_NEG -14426.950408889634f  // -10000 * log2(e)

typedef __attribute__((ext_vector_type(8))) short short8v;   // 8 bf16 (4 VGPR) MFMA operand
typedef __attribute__((ext_vector_type(4))) float f32x4;     // MFMA accumulator
typedef __attribute__((ext_vector_type(4))) uint32_t u32x4;

static __device__ __forceinline__ uint16_t bf16rn(float f) {
  uint32_t u = __builtin_bit_cast(uint32_t, f);
  u += 0x7FFFu + ((u >> 16) & 1u);          // round-to-nearest-even
  return (uint16_t)(u >> 16);
}
static __device__ __forceinline__ float bf16f(uint16_t h) {
  return __builtin_bit_cast(float, (uint32_t)h << 16);
}
static __device__ __forceinline__ float exp2a(float x) {
  float r; asm("v_exp_f32 %0, %1" : "=v"(r) : "v"(x)); return r;
}
static __device__ __forceinline__ uint32_t cvtpk(float lo, float hi) {
  uint32_t r; asm("v_cvt_pk_bf16_f32 %0, %1, %2" : "=v"(r) : "v"(lo), "v"(hi)); return r;
}
static __device__ __forceinline__ void gl_lds16(const void* g, void* l) {
  __builtin_amdgcn_global_load_lds((const __attribute__((address_space(1))) void*)g,
                                   (__attribute__((address_space(3))) void*)l, 16, 0, 0);
}

// ---------------- fused pre-pass: pack | kfrag | tab2, partitioned by blockIdx ----------
// bid [0,8192): pack (rel_id | mask<<5) -> byte
// bid [8192,10240): K (bf16, pre-scaled LOG2E_8) + V (bf16) MFMA-fragment panels
// bid [10240,11264): f16 score table via MFMA (hi/lo E and Q)
// All three are mutually independent (disjoint outputs, read-only inputs).
__global__ __launch_bounds__(256) void prep_kernel(
    const int* __restrict__ ids, const int* __restrict__ msk,
    const float* __restrict__ Kg, const float* __restrict__ Vg,
    const float* __restrict__ Qg, const float* __restrict__ Eg,
    const float* __restrict__ biasg, uint32_t* __restrict__ outp,
    uint8_t* __restrict__ frag, __half* __restrict__ tabg) {
  const int tid = threadIdx.x;
  if (blockIdx.x < 8192) {
    // ---- pack (R11-verbatim) ----
    const int i = blockIdx.x * 256 + tid;
    int4 a = reinterpret_cast<const int4*>(ids)[i];
    int4 m = reinterpret_cast<const int4*>(msk)[i];
    uint32_t v = (uint32_t)((a.x | (m.x << 5)) & 0x3f)
               | ((uint32_t)((a.y | (m.y << 5)) & 0x3f) << 8)
               | ((uint32_t)((a.z | (m.z << 5)) & 0x3f) << 16)
               | ((uint32_t)((a.w | (m.w << 5)) & 0x3f) << 24);
    outp[i] = v;
  } else if (blockIdx.x < 10240) {
    // ---- kfrag6 (R11-verbatim) ----
    const int bid = blockIdx.x - 8192;
    const int c = bid & 63;
    const int h = (bid >> 6) & 15;
    const int b = bid >> 10;
    uint8_t* panel = frag + (size_t)(b * 16 + h) * 524288u + (size_t)c * 8192u;
    uint4* kf = reinterpret_cast<uint4*>(panel);
    uint4* vf = reinterpret_cast<uint4*>(panel + 4096);
    const int sdq = tid & 7, srow = (tid >> 3) & 15, stile = tid >> 7;
    const int sg = sdq & 3, sdm = sdq >> 2;
    const float* kp = Kg + ((((size_t)b * Kn) + c * 32 + stile * 16 + srow) * Hn + h) * Dn + (sdm * 32 + sg * 4);
    const float4 x0 = *reinterpret_cast<const float4*>(kp);
    const float4 x1 = *reinterpret_cast<const float4*>(kp + 16);
    const float xs0[4] = {x0.x * LOG2E_8, x0.y * LOG2E_8, x0.z * LOG2E_8, x0.w * LOG2E_8};
    const float xs1[4] = {x1.x * LOG2E_8, x1.y * LOG2E_8, x1.z * LOG2E_8, x1.w * LOG2E_8};
    uint4 uh;
    uh.x = bf16rn(xs0[0]) | ((uint32_t)bf16rn(xs0[1]) << 16);
    uh.y = bf16rn(xs0[2]) | ((uint32_t)bf16rn(xs0[3]) << 16);
    uh.z = bf16rn(xs1[0]) | ((uint32_t)bf16rn(xs1[1]) << 16);
    uh.w = bf16rn(xs1[2]) | ((uint32_t)bf16rn(xs1[3]) << 16);
    kf[(stile * 2 + sdm) * 64 + (srow + 16 * sg)] = uh;
    const int vd = tid & 63, vkq = tid >> 6;
    const float* vp = Vg + ((((size_t)b * Kn) + c * 32 + vkq * 4) * Hn + h) * Dn + vd;
    float v0[4], v1[4];
#pragma unroll
    for (int i = 0; i < 4; ++i) {
      v0[i] = vp[i * (Hn * Dn)];
      v1[i] = vp[(16 + i) * (Hn * Dn)];
    }
    uint4 uv;
    uv.x = bf16rn(v0[0]) | ((uint32_t)bf16rn(v0[1]) << 16);
    uv.y = bf16rn(v0[2]) | ((uint32_t)bf16rn(v0[3]) << 16);
    uv.z = bf16rn(v1[0]) | ((uint32_t)bf16rn(v1[1]) << 16);
    uv.w = bf16rn(v1[2]) | ((uint32_t)bf16rn(v1[3]) << 16);
    vf[(vd >> 4) * 64 + (vd & 15) + 16 * vkq] = uv;
  } else {
    // ---- tab2 (R11-verbatim): f16 score table via MFMA (hi/lo E and Q) ----
    const int bid = blockIdx.x - 10240;
    const int lane = tid & 63;
    const int w = tid >> 6;
    const int qr = lane & 15;
    const int g = lane >> 4;
    const int qt = bid & 31;
    const int h = (bid >> 5) & 15;
    const int b = bid >> 9;
    const int q0 = qt * 64 + w * 16;

    short8v eh[2][2], el[2][2];
#pragma unroll
    for (int rt = 0; rt < 2; ++rt)
#pragma unroll
      for (int dm = 0; dm < 2; ++dm) {
        const float* ep = Eg + (((size_t)(rt * 16 + qr) * Hn + h) * Dn) + dm * 32 + 4 * g;
        const float4 x0 = *reinterpret_cast<const float4*>(ep);
        const float4 x1 = *reinterpret_cast<const float4*>(ep + 16);
        const float xs[8] = {x0.x * LOG2E_8, x0.y * LOG2E_8, x0.z * LOG2E_8, x0.w * LOG2E_8,
                             x1.x * LOG2E_8, x1.y * LOG2E_8, x1.z * LOG2E_8, x1.w * LOG2E_8};
#pragma unroll
        for (int j = 0; j < 8; ++j) {
          const uint16_t hi = bf16rn(xs[j]);
          eh[rt][dm][j] = (short)hi;
          el[rt][dm][j] = (short)bf16rn(xs[j] - bf16f(hi));
        }
      }
    short8v qh[2], ql[2];
#pragma unroll
    for (int dm = 0; dm < 2; ++dm) {
      const float* qp = Qg + (((size_t)b * Qn + q0 + qr) * Hn + h) * Dn + dm * 32 + 4 * g;
      const float4 x0 = *reinterpret_cast<const float4*>(qp);
      const float4 x1 = *reinterpret_cast<const float4*>(qp + 16);
      const float xs[8] = {x0.x, x0.y, x0.z, x0.w, x1.x, x1.y, x1.z, x1.w};
#pragma unroll
      for (int j = 0; j < 8; ++j) {
        const uint16_t hi = bf16rn(xs[j]);
        qh[dm][j] = (short)hi;
        ql[dm][j] = (short)bf16rn(xs[j] - bf16f(hi));
      }
    }
#pragma unroll
    for (int rt = 0; rt < 2; ++rt) {
      f32x4 d;
#pragma unroll
      for (int j = 0; j < 4; ++j)
        d[j] = LOG2E_8 * biasg[(rt * 16 + 4 * g + j) * Hn + h];
#pragma unroll
      for (int dm = 0; dm < 2; ++dm) {
        d = __builtin_amdgcn_mfma_f32_16x16x32_bf16(eh[rt][dm], qh[dm], d, 0, 0, 0);
        d = __builtin_amdgcn_mfma_f32_16x16x32_bf16(el[rt][dm], qh[dm], d, 0, 0, 0);
        d = __builtin_amdgcn_mfma_f32_16x16x32_bf16(eh[rt][dm], ql[dm], d, 0, 0, 0);
      }
      const size_t rowo = ((size_t)(b * 16 + h) * 2048 + q0 + qr) * 64;
      union { ushort4 u4; __half hh[4]; } um, uu;
#pragma unroll
      for (int j = 0; j < 4; ++j) {
        um.hh[j] = __float2half(d[j] + MASK_NEG);
        uu.hh[j] = __float2half(d[j]);
      }
      *reinterpret_cast<ushort4*>(&tabg[rowo + rt * 16 + 4 * g]) = um.u4;
      *reinterpret_cast<ushort4*>(&tabg[rowo + 32 + rt * 16 + 4 * g]) = uu.u4;
    }
  }
}

// ---------------- attn9 (R11-verbatim, verified 87.7 us): 3-buffer counted-vmcnt --------
// Waves 0-3: keys [0,1024); waves 4-7: keys [1024,2048). Same 128-q tile.
__global__ __launch_bounds__(512, 4) void attn9_kernel(
    const float* __restrict__ Qg, const uint8_t* __restrict__ packed,
    const uint8_t* __restrict__ kfragp, const __half* __restrict__ tabg,
    float* __restrict__ outg) {
  // LDS (disjoint): [0,16384) tab f16[128][64]
  //   [16384,40960)  half0: 3 bufs x 8192
  //   [40960,65536)  half1: 3 bufs x 8192
  // Epilogue reuse: acc1 f32[128][64] at [16384,49152); l1 f32[128] at [0,512)
  __shared__ alignas(16) char smem[65536];
  const int tid = threadIdx.x;
  const int lane = tid & 63;
  const int w = tid >> 6;     // 0..7
  const int w4 = w & 3;
  const int ks = w >> 2;
  const int qr = lane & 15;
  const int g = lane >> 4;

  // XCD-aware swizzle (512 blocks = 8 XCDs x 64)
  const int wi = (blockIdx.x & 7) * 64 + (blockIdx.x >> 3);
  const int qt = wi & 15;
  const int h = (wi >> 4) & 15;
  const int b = wi >> 8;
  const int q0 = qt * 128;

  char* const myhalf = smem + 16384 + ks * 24576;
  char* bA = myhalf;           // chunk c   (read)
  char* bB = myhalf + 8192;    // chunk c+1 (staged, landing)
  char* bC = myhalf + 16384;   // chunk c+2 (stage target)

  // ---- packed-byte row bases; load pc (iter 0) FIRST so later gl_lds stay newest ----
  int64_t prow[2];
  int trow[2];
#pragma unroll
  for (int t = 0; t < 2; ++t) {
    prow[t] = ((int64_t)(b * Qn + q0 + w4 * 32 + t * 16 + qr)) * Kn + ks * 1024 + 4 * g;
    trow[t] = (w4 * 32 + t * 16 + qr) * 64;
  }
  uint32_t pc[2][2], pn[2][2] = {{0u, 0u}, {0u, 0u}};
#pragma unroll
  for (int t = 0; t < 2; ++t)
#pragma unroll
    for (int st = 0; st < 2; ++st)
      pc[t][st] = *reinterpret_cast<const uint32_t*>(packed + prow[t] + st * 16);

  // ---- entry staging: tab tile (16 KB linear) + chunks 0,1 of my half ----
  {
    const uint8_t* tsrc = reinterpret_cast<const uint8_t*>(
        tabg + ((size_t)(b * 16 + h) * 2048 + q0) * 64);
    char* ld = smem + w * 2048;
    gl_lds16(tsrc + (size_t)w * 2048 + (size_t)lane * 16, ld);
    gl_lds16(tsrc + (size_t)w * 2048 + 1024 + (size_t)lane * 16, ld + 1024);
  }
  const uint8_t* sbase = kfragp + (size_t)(b * 16 + h) * 524288u +
                         (size_t)(ks * 32) * 8192u + (size_t)w4 * 2048 + (size_t)lane * 16;
  {
    char* ld0 = bA + w4 * 2048;
    gl_lds16(sbase, ld0);
    gl_lds16(sbase + 1024, ld0 + 1024);
    char* ld1 = bB + w4 * 2048;
    gl_lds16(sbase + 8192, ld1);
    gl_lds16(sbase + 8192 + 1024, ld1 + 1024);
  }

  // ---- Q fragments direct from global (bf16 via cvtpk; R8-verified mapping) ----
  short8v qhi[2][2];
#pragma unroll
  for (int t = 0; t < 2; ++t)
#pragma unroll
    for (int dm = 0; dm < 2; ++dm) {
      const float* qp = Qg + (((size_t)b * Qn + q0 + w4 * 32 + t * 16 + qr) * Hn + h) * Dn +
                        dm * 32 + 4 * g;
      const float4 x0 = *reinterpret_cast<const float4*>(qp);
      const float4 x1 = *reinterpret_cast<const float4*>(qp + 16);
      u32x4 u;
      u[0] = cvtpk(x0.x, x0.y); u[1] = cvtpk(x0.z, x0.w);
      u[2] = cvtpk(x1.x, x1.y); u[3] = cvtpk(x1.z, x1.w);
      qhi[t][dm] = __builtin_bit_cast(short8v, u);
    }

  asm volatile("s_waitcnt vmcnt(0)" ::: "memory");
  __builtin_amdgcn_sched_barrier(0);
  __syncthreads();

  const short8v ones = {(short)0x3F80, (short)0x3F80, (short)0x3F80, (short)0x3F80,
                        (short)0x3F80, (short)0x3F80, (short)0x3F80, (short)0x3F80};
  const __half* tabh = reinterpret_cast<const __half*>(smem);

  f32x4 acc[2][4] = {{{0.f,0.f,0.f,0.f},{0.f,0.f,0.f,0.f},{0.f,0.f,0.f,0.f},{0.f,0.f,0.f,0.f}},
                     {{0.f,0.f,0.f,0.f},{0.f,0.f,0.f,0.f},{0.f,0.f,0.f,0.f},{0.f,0.f,0.f,0.f}}};
  f32x4 accl[2] = {{0.f,0.f,0.f,0.f},{0.f,0.f,0.f,0.f}};

  for (int c = 0; c < 32; ++c) {
    // (1) issue next packed bytes (older than the gl_lds below -> their wait won't drain it)
    if (c + 1 < 32) {
      const int64_t kb = (int64_t)(c + 1) * 32;
#pragma unroll
      for (int t = 0; t < 2; ++t)
#pragma unroll
        for (int st = 0; st < 2; ++st)
          pn[t][st] = *reinterpret_cast<const uint32_t*>(packed + prow[t] + kb + st * 16);
    }
    // (2) issue stage of chunk c+2 (stays in flight across the barrier)
    if (c + 2 < 32) {
      const uint8_t* gs = sbase + (size_t)(c + 2) * 8192u;
      char* ld = bC + w4 * 2048;
      gl_lds16(gs, ld);
      gl_lds16(gs + 1024, ld + 1024);
    }

    // ---- QK^T (swapped, single bf16 pre-scaled) on chunk c ----
    const short8v* kfs = reinterpret_cast<const short8v*>(bA);
    f32x4 s[2][2] = {{{0.f,0.f,0.f,0.f},{0.f,0.f,0.f,0.f}},
                     {{0.f,0.f,0.f,0.f},{0.f,0.f,0.f,0.f}}};
    __builtin_amdgcn_s_setprio(1);
#pragma unroll
    for (int dm = 0; dm < 2; ++dm) {
      const short8v k0 = kfs[dm * 64 + lane];
      const short8v k1 = kfs[(2 + dm) * 64 + lane];
#pragma unroll
      for (int t = 0; t < 2; ++t) {
        s[t][0] = __builtin_amdgcn_mfma_f32_16x16x32_bf16(k0, qhi[t][dm], s[t][0], 0, 0, 0);
        s[t][1] = __builtin_amdgcn_mfma_f32_16x16x32_bf16(k1, qhi[t][dm], s[t][1], 0, 0, 0);
      }
    }
    __builtin_amdgcn_s_setprio(0);

    // V fragments
    const short8v* vfs = reinterpret_cast<const short8v*>(bA + 4096);
    short8v vv[4];
#pragma unroll
    for (int dt = 0; dt < 4; ++dt) vv[dt] = vfs[dt * 64 + lane];

    // ---- per-tile: table gather + raw exp2 + PV + ones-MFMA row-sum ----
#pragma unroll
    for (int t = 0; t < 2; ++t) {
      float pv[8];
#pragma unroll
      for (int i = 0; i < 8; ++i) {
        const int st = i >> 2, r = i & 3;
        const uint32_t v = (pc[t][st] >> (8 * r)) & 63u;
        pv[i] = exp2a(s[t][st][r] + __half2float(tabh[trow[t] + (int)v]));
      }
      u32x4 pu;
      pu[0] = cvtpk(pv[0], pv[1]); pu[1] = cvtpk(pv[2], pv[3]);
      pu[2] = cvtpk(pv[4], pv[5]); pu[3] = cvtpk(pv[6], pv[7]);
      const short8v pa = __builtin_bit_cast(short8v, pu);
      __builtin_amdgcn_s_setprio(1);
#pragma unroll
      for (int dt = 0; dt < 4; ++dt)
        acc[t][dt] = __builtin_amdgcn_mfma_f32_16x16x32_bf16(pa, vv[dt], acc[t][dt], 0, 0, 0);
      accl[t] = __builtin_amdgcn_mfma_f32_16x16x32_bf16(pa, ones, accl[t], 0, 0, 0);
      __builtin_amdgcn_s_setprio(0);
    }

    // (3) pc <- pn: compiler wait here retires pn AND the older chunk-(c+1) gl_lds
    if (c + 1 < 32) {
#pragma unroll
      for (int t = 0; t < 2; ++t) { pc[t][0] = pn[t][0]; pc[t][1] = pn[t][1]; }
    }

    // (4) guarantee chunk c+1 staged; allow the 6 newest (4 pn + 2 gl_lds) in flight
    if (c < 30) {
      asm volatile("s_waitcnt vmcnt(6)" ::: "memory");
    } else {
      asm volatile("s_waitcnt vmcnt(0)" ::: "memory");
    }
    __builtin_amdgcn_sched_barrier(0);
    __syncthreads();
    char* tmp = bA; bA = bB; bB = bC; bC = tmp;
  }

  // ---- epilogue: in-block merge (ks=1 partials -> LDS; ks=0 combines + stores) ----
  float* const acc1s = reinterpret_cast<float*>(smem + 16384);  // [128][64]
  float* const l1s   = reinterpret_cast<float*>(smem);          // [128]
  if (ks == 1) {
#pragma unroll
    for (int t = 0; t < 2; ++t) {
#pragma unroll
      for (int dt = 0; dt < 4; ++dt)
#pragma unroll
        for (int r = 0; r < 4; ++r)
          acc1s[(w4 * 32 + t * 16 + 4 * g + r) * 64 + dt * 16 + qr] = acc[t][dt][r];
#pragma unroll
      for (int r = 0; r < 4; ++r)
        l1s[w4 * 32 + t * 16 + 4 * g + r] = accl[t][r];  // same value across qr lanes
    }
  }
  __syncthreads();
  if (ks == 0) {
#pragma unroll
    for (int t = 0; t < 2; ++t) {
      const f32x4 l1v = *reinterpret_cast<const f32x4*>(&l1s[w4 * 32 + t * 16 + 4 * g]);
      f32x4 linv;
#pragma unroll
      for (int r = 0; r < 4; ++r) linv[r] = 1.0f / (accl[t][r] + l1v[r]);
#pragma unroll
      for (int dt = 0; dt < 4; ++dt)
#pragma unroll
        for (int r = 0; r < 4; ++r) {
          const int lrow = w4 * 32 + t * 16 + 4 * g + r;
          const float o = (acc[t][dt][r] + acc1s[lrow * 64 + dt * 16 + qr]) * linv[r];
          outg[(((size_t)b * Qn + q0 + lrow) * Hn + h) * Dn + dt * 16 + qr] = o;
        }
    }
  }
}

// ---------------- fallback (ws too small): fully self-contained, no scratch ----------------
__global__ __launch_bounds__(256) void attn_old_kernel(
    const float* __restrict__ Qg, const float* __restrict__ Kg,
    const float* __restrict__ Vg, const int* __restrict__ maskg,
    const int* __restrict__ idsg, const float* __restrict__ Eg,
    const float* __restrict__ biasg, float* __restrict__ outg) {
  __shared__ alignas(16) char smem[34304];
  float* const allrel = reinterpret_cast<float*>(smem);
  float* const q_lds  = reinterpret_cast<float*>(smem + 8448);
  float* const et_lds = reinterpret_cast<float*>(smem + 25856);
  uint4* const kfrag  = reinterpret_cast<uint4*>(smem + 8448);
  uint4* const vfrag  = reinterpret_cast<uint4*>(smem + 16640);

  const int tid  = threadIdx.x;
  const int lane = tid & 63;
  const int w    = tid >> 6;
  const int qr   = lane & 15;
  const int g    = lane >> 4;

  const int bid = blockIdx.x;
  const int h  = bid & 15;
  const int qt = (bid >> 4) & 31;
  const int b  = bid >> 9;
  const int q0 = qt * 64;

  {
    const int row = tid >> 2, dq = (tid & 3) * 16;
    const float4* s4 =
        reinterpret_cast<const float4*>(Qg + (((b * Qn) + q0 + row) * Hn + h) * Dn + dq);
    float4* dst = reinterpret_cast<float4*>(&q_lds[row * 68 + dq]);
#pragma unroll
    for (int i = 0; i < 4; ++i) dst[i] = s4[i];
  }
  {
    const int r = tid >> 3, d0 = (tid & 7) * 8;
    const float* src = Eg + ((r * Hn + h) * Dn + d0);
#pragma unroll
    for (int i = 0; i < 8; ++i) et_lds[(d0 + i) * 33 + r] = src[i];
  }
  __syncthreads();

  const int qloc = w * 16 + qr;
  short8v qhi[2], qlo[2];
#pragma unroll
  for (int dm = 0; dm < 2; ++dm) {
#pragma unroll
    for (int j = 0; j < 8; ++j) {
      const int dl = (j < 4) ? (4 * g + j) : (16 + 4 * g + (j - 4));
      const float x = q_lds[qloc * 68 + dm * 32 + dl];
      const uint16_t hi = bf16rn(x);
      qhi[dm][j] = (short)hi;
      qlo[dm][j] = (short)bf16rn(x - bf16f(hi));
    }
  }

  {
    const int r = tid & 31, q8 = tid >> 5;
    float acc[8] = {0.f, 0.f, 0.f, 0.f, 0.f, 0.f, 0.f, 0.f};
    const float bias = biasg[r * Hn + h];
    for (int d = 0; d < 64; ++d) {
      const float e = et_lds[d * 33 + r];
#pragma unroll
      for (int i = 0; i < 8; ++i) acc[i] += e * q_lds[(q8 * 8 + i) * 68 + d];
    }
#pragma unroll
    for (int i = 0; i < 8; ++i)
      allrel[(q8 * 8 + i) * 33 + r] = 0.125f * (acc[i] + bias);
  }
  __syncthreads();

  const int sdq = tid & 7, srow = (tid >> 3) & 15, stile = tid >> 7;
  const int sg = sdq & 3, sdm = sdq >> 2;
  int koff = (((b * Kn) + stile * 16 + srow) * Hn + h) * Dn + (sdm * 32 + sg * 4);
  const int kslotH = (stile * 2 + sdm) * 64 + (srow + 16 * sg);
  const int kslotL = (4 + stile * 2 + sdm) * 64 + (srow + 16 * sg);
  const int vd = tid & 63, vkq = tid >> 6;
  int voff = (((b * Kn) + vkq * 4) * Hn + h) * Dn + vd;
  const int vslot = (vd >> 4) * 64 + (vd & 15) + 16 * vkq;

  const int qglob = q0 + qloc;
  const int prow = (b * Qn + qglob) * Kn + 4 * g;

  f32x4 acc[4] = {{0.f,0.f,0.f,0.f},{0.f,0.f,0.f,0.f},{0.f,0.f,0.f,0.f},{0.f,0.f,0.f,0.f}};
  float mrun = -1e30f, lrun = 0.f;

  const short8v* kfs = reinterpret_cast<const short8v*>(kfrag);
  const short8v* vfs = reinterpret_cast<const short8v*>(vfrag);

  for (int c = 0; c < 64; ++c) {
    const int kb = c * 32;
    __syncthreads();
    {
      const float4 x0 = *reinterpret_cast<const float4*>(Kg + koff);
      const float4 x1 = *reinterpret_cast<const float4*>(Kg + koff + 16);
      koff += 32 * Hn * Dn;
      const float xs0[4] = {x0.x, x0.y, x0.z, x0.w};
      const float xs1[4] = {x1.x, x1.y, x1.z, x1.w};
      uint16_t hh[8], ll[8];
#pragma unroll
      for (int i = 0; i < 4; ++i) {
        const uint16_t h0 = bf16rn(xs0[i]);
        const uint16_t h1 = bf16rn(xs1[i]);
        hh[i] = h0; hh[4 + i] = h1;
        ll[i] = bf16rn(xs0[i] - bf16f(h0));
        ll[4 + i] = bf16rn(xs1[i] - bf16f(h1));
      }
      uint4 uh, ul;
      uh.x = hh[0] | ((uint32_t)hh[1] << 16); uh.y = hh[2] | ((uint32_t)hh[3] << 16);
      uh.z = hh[4] | ((uint32_t)hh[5] << 16); uh.w = hh[6] | ((uint32_t)hh[7] << 16);
      ul.x = ll[0] | ((uint32_t)ll[1] << 16); ul.y = ll[2] | ((uint32_t)ll[3] << 16);
      ul.z = ll[4] | ((uint32_t)ll[5] << 16); ul.w = ll[6] | ((uint32_t)ll[7] << 16);
      kfrag[kslotH] = uh;
      kfrag[kslotL] = ul;
    }
    {
      float v0[4], v1[4];
#pragma unroll
      for (int i = 0; i < 4; ++i) {
        v0[i] = Vg[voff + i * (Hn * Dn)];
        v1[i] = Vg[voff + 16 * Hn * Dn + i * (Hn * Dn)];
      }
      voff += 32 * Hn * Dn;
      uint4 uv;
      uv.x = bf16rn(v0[0]) | ((uint32_t)bf16rn(v0[1]) << 16);
      uv.y = bf16rn(v0[2]) | ((uint32_t)bf16rn(v0[3]) << 16);
      uv.z = bf16rn(v1[0]) | ((uint32_t)bf16rn(v1[1]) << 16);
      uv.w = bf16rn(v1[2]) | ((uint32_t)bf16rn(v1[3]) << 16);
      vfrag[vslot] = uv;
    }
    __syncthreads();

    f32x4 s0 = {0.f, 0.f, 0.f, 0.f}, s1 = {0.f, 0.f, 0.f, 0.f};
#pragma unroll
    for (int dm = 0; dm < 2; ++dm) {
      const short8v k0h = kfs[(dm) * 64 + lane];
      const short8v k1h = kfs[(2 + dm) * 64 + lane];
      const short8v k0l = kfs[(4 + dm) * 64 + lane];
      const short8v k1l = kfs[(6 + dm) * 64 + lane];
      s0 = __builtin_amdgcn_mfma_f32_16x16x32_bf16(k0h, qhi[dm], s0, 0, 0, 0);
      s1 = __builtin_amdgcn_mfma_f32_16x16x32_bf16(k1h, qhi[dm], s1, 0, 0, 0);
      s0 = __builtin_amdgcn_mfma_f32_16x16x32_bf16(k0h, qlo[dm], s0, 0, 0, 0);
      s1 = __builtin_amdgcn_mfma_f32_16x16x32_bf16(k1h, qlo[dm], s1, 0, 0, 0);
      s0 = __builtin_amdgcn_mfma_f32_16x16x32_bf16(k0l, qhi[dm], s0, 0, 0, 0);
      s1 = __builtin_amdgcn_mfma_f32_16x16x32_bf16(k1l, qhi[dm], s1, 0, 0, 0);
    }

    float sv[8];
    {
      const int ib = prow + kb;
      const int4 i0 = *reinterpret_cast<const int4*>(idsg + ib);
      const int4 i1 = *reinterpret_cast<const int4*>(idsg + ib + 16);
      const int4 m0 = *reinterpret_cast<const int4*>(maskg + ib);
      const int4 m1 = *reinterpret_cast<const int4*>(maskg + ib + 16);
      const int ia0[4] = {i0.x, i0.y, i0.z, i0.w};
      const int ia1[4] = {i1.x, i1.y, i1.z, i1.w};
      const int ma0[4] = {m0.x, m0.y, m0.z, m0.w};
      const int ma1[4] = {m1.x, m1.y, m1.z, m1.w};
#pragma unroll
      for (int r = 0; r < 4; ++r) {
        sv[r]     = 0.125f * s0[r] + allrel[qloc * 33 + ia0[r]] + (ma0[r] ? 0.f : -10000.f);
        sv[4 + r] = 0.125f * s1[r] + allrel[qloc * 33 + ia1[r]] + (ma1[r] ? 0.f : -10000.f);
      }
    }

    float m8 = sv[0];
#pragma unroll
    for (int i = 1; i < 8; ++i) m8 = fmaxf(m8, sv[i]);
    m8 = fmaxf(m8, __shfl_xor(m8, 16));
    m8 = fmaxf(m8, __shfl_xor(m8, 32));
    const float mnew = fmaxf(mrun, m8);
    const float sc = __expf(mrun - mnew);
    mrun = mnew;
    float pv[8];
    float ps = 0.f;
#pragma unroll
    for (int i = 0; i < 8; ++i) { pv[i] = __expf(sv[i] - mnew); ps += pv[i]; }
    ps += __shfl_xor(ps, 16);
    ps += __shfl_xor(ps, 32);
    lrun = lrun * sc + ps;

    f32x4 scv;
#pragma unroll
    for (int r = 0; r < 4; ++r) scv[r] = __shfl(sc, 4 * g + r);
#pragma unroll
    for (int dt = 0; dt < 4; ++dt) acc[dt] *= scv;

    short8v pa;
#pragma unroll
    for (int i = 0; i < 8; ++i) pa[i] = (short)bf16rn(pv[i]);
#pragma unroll
    for (int dt = 0; dt < 4; ++dt)
      acc[dt] = __builtin_amdgcn_mfma_f32_16x16x32_bf16(pa, vfs[dt * 64 + lane], acc[dt], 0, 0, 0);
  }

  const float linv = 1.0f / lrun;
  f32x4 lv;
#pragma unroll
  for (int r = 0; r < 4; ++r) lv[r] = __shfl(linv, 4 * g + r);
#pragma unroll
  for (int dt = 0; dt < 4; ++dt) {
#pragma unroll
    for (int r = 0; r < 4; ++r) {
      const int qrow = q0 + w * 16 + 4 * g + r;
      outg[(((b * Qn) + qrow) * Hn + h) * Dn + dt * 16 + qr] = acc[dt][r] * lv[r];
    }
  }
}

extern "C" void kernel_launch(void* const* d_in, const int* in_sizes, int n_in,
                              void* d_out, int out_size, void* d_ws, size_t ws_size,
                              hipStream_t stream) {
  const float* Qg    = (const float*)d_in[0];
  const float* Kg    = (const float*)d_in[1];
  const float* Vg    = (const float*)d_in[2];
  const int*   maskg = (const int*)d_in[3];
  const int*   idsg  = (const int*)d_in[4];
  const float* Eg    = (const float*)d_in[5];
  const float* biasg = (const float*)d_in[6];
  float* outg = (float*)d_out;

  // ws layout
  const size_t oPack = 0;                 // 8,388,608
  const size_t oK    = 8388608;           // +16,777,216 -> 25,165,824
  const size_t oT    = 25165824;          // +8,388,608  -> 33,554,432
  const size_t need = 33554432;

  uint8_t* ws = (uint8_t*)d_ws;

  if (ws_size >= need) {
    // fused prepass: 8192 (pack) + 2048 (kfrag) + 1024 (tab2) = 11264 blocks
    prep_kernel<<<11264, 256, 0, stream>>>(
        idsg, maskg, Kg, Vg, Qg, Eg, biasg,
        (uint32_t*)(ws + oPack), ws + oK, (__half*)(ws + oT));
    attn9_kernel<<<Bn * Hn * (Qn / 128), 512, 0, stream>>>(
        Qg, ws + oPack, ws + oK, (const __half*)(ws + oT), outg);
  } else {
    attn_old_kernel<<<Bn * Hn * (Qn / 64), 256, 0, stream>>>(
        Qg, Kg, Vg, maskg, idsg, Eg, biasg, outg);
  }
}

// Round 16
// 106.376 us; speedup vs baseline: 1.2250x; 1.0077x over previous
//
#include <hip/hip_runtime.h>
#include <hip/hip_fp16.h>
#include <stdint.h>

// Problem constants (fixed by the reference)
#define Bn 2
#define Qn 2048
#define Kn 2048
#define Hn 16
#define Dn 64
#define Rn 32

#define LOG2E_8 0.18033688011112042f   // 0.125 * log2(e)
#define MASK_NEG -14426.950408889634f  // -10000 * log2(e)

typedef __attribute__((ext_vector_type(8))) short short8v;   // 8 bf16 (4 VGPR) MFMA operand
typedef __attribute__((ext_vector_type(4))) float f32x4;     // MFMA accumulator
typedef __attribute__((ext_vector_type(4))) uint32_t u32x4;

static __device__ __forceinline__ uint16_t bf16rn(float f) {
  uint32_t u = __builtin_bit_cast(uint32_t, f);
  u += 0x7FFFu + ((u >> 16) & 1u);          // round-to-nearest-even
  return (uint16_t)(u >> 16);
}
static __device__ __forceinline__ float bf16f(uint16_t h) {
  return __builtin_bit_cast(float, (uint32_t)h << 16);
}
static __device__ __forceinline__ float exp2a(float x) {
  float r; asm("v_exp_f32 %0, %1" : "=v"(r) : "v"(x)); return r;
}
static __device__ __forceinline__ uint32_t cvtpk(float lo, float hi) {
  uint32_t r; asm("v_cvt_pk_bf16_f32 %0, %1, %2" : "=v"(r) : "v"(lo), "v"(hi)); return r;
}
// s + (f16 in low bits of hraw), single op: v_fma_mix_f32 (exact: 1.0 * f16 + f32)
static __device__ __forceinline__ float addh(uint32_t hraw, float s) {
  float r;
  asm("v_fma_mix_f32 %0, %1, 1.0, %2 op_sel_hi:[1,0,0]" : "=v"(r) : "v"(hraw), "v"(s));
  return r;
}
static __device__ __forceinline__ void gl_lds16(const void* g, void* l) {
  __builtin_amdgcn_global_load_lds((const __attribute__((address_space(1))) void*)g,
                                   (__attribute__((address_space(3))) void*)l, 16, 0, 0);
}

// ---------------- fused pre-pass: pack | kfrag | tab2, partitioned by blockIdx ----------
// bid [0,8192): pack -> BYTE OFFSET into 128B tab row: (id<<1)|(mask<<6)
// bid [8192,10240): K (bf16, pre-scaled LOG2E_8) + V (bf16) MFMA-fragment panels
// bid [10240,11264): f16 score table via MFMA (hi/lo E and Q)
__global__ __launch_bounds__(256) void prep_kernel(
    const int* __restrict__ ids, const int* __restrict__ msk,
    const float* __restrict__ Kg, const float* __restrict__ Vg,
    const float* __restrict__ Qg, const float* __restrict__ Eg,
    const float* __restrict__ biasg, uint32_t* __restrict__ outp,
    uint8_t* __restrict__ frag, __half* __restrict__ tabg) {
  const int tid = threadIdx.x;
  if (blockIdx.x < 8192) {
    // ---- pack: byte = (id<<1) | (mask<<6)  (direct byte offset, saves lshl in gather) ----
    const int i = blockIdx.x * 256 + tid;
    int4 a = reinterpret_cast<const int4*>(ids)[i];
    int4 m = reinterpret_cast<const int4*>(msk)[i];
    uint32_t v = (uint32_t)(((a.x << 1) | (m.x << 6)) & 0x7f)
               | ((uint32_t)(((a.y << 1) | (m.y << 6)) & 0x7f) << 8)
               | ((uint32_t)(((a.z << 1) | (m.z << 6)) & 0x7f) << 16)
               | ((uint32_t)(((a.w << 1) | (m.w << 6)) & 0x7f) << 24);
    outp[i] = v;
  } else if (blockIdx.x < 10240) {
    // ---- kfrag6 (R15-verbatim) ----
    const int bid = blockIdx.x - 8192;
    const int c = bid & 63;
    const int h = (bid >> 6) & 15;
    const int b = bid >> 10;
    uint8_t* panel = frag + (size_t)(b * 16 + h) * 524288u + (size_t)c * 8192u;
    uint4* kf = reinterpret_cast<uint4*>(panel);
    uint4* vf = reinterpret_cast<uint4*>(panel + 4096);
    const int sdq = tid & 7, srow = (tid >> 3) & 15, stile = tid >> 7;
    const int sg = sdq & 3, sdm = sdq >> 2;
    const float* kp = Kg + ((((size_t)b * Kn) + c * 32 + stile * 16 + srow) * Hn + h) * Dn + (sdm * 32 + sg * 4);
    const float4 x0 = *reinterpret_cast<const float4*>(kp);
    const float4 x1 = *reinterpret_cast<const float4*>(kp + 16);
    const float xs0[4] = {x0.x * LOG2E_8, x0.y * LOG2E_8, x0.z * LOG2E_8, x0.w * LOG2E_8};
    const float xs1[4] = {x1.x * LOG2E_8, x1.y * LOG2E_8, x1.z * LOG2E_8, x1.w * LOG2E_8};
    uint4 uh;
    uh.x = bf16rn(xs0[0]) | ((uint32_t)bf16rn(xs0[1]) << 16);
    uh.y = bf16rn(xs0[2]) | ((uint32_t)bf16rn(xs0[3]) << 16);
    uh.z = bf16rn(xs1[0]) | ((uint32_t)bf16rn(xs1[1]) << 16);
    uh.w = bf16rn(xs1[2]) | ((uint32_t)bf16rn(xs1[3]) << 16);
    kf[(stile * 2 + sdm) * 64 + (srow + 16 * sg)] = uh;
    const int vd = tid & 63, vkq = tid >> 6;
    const float* vp = Vg + ((((size_t)b * Kn) + c * 32 + vkq * 4) * Hn + h) * Dn + vd;
    float v0[4], v1[4];
#pragma unroll
    for (int i = 0; i < 4; ++i) {
      v0[i] = vp[i * (Hn * Dn)];
      v1[i] = vp[(16 + i) * (Hn * Dn)];
    }
    uint4 uv;
    uv.x = bf16rn(v0[0]) | ((uint32_t)bf16rn(v0[1]) << 16);
    uv.y = bf16rn(v0[2]) | ((uint32_t)bf16rn(v0[3]) << 16);
    uv.z = bf16rn(v1[0]) | ((uint32_t)bf16rn(v1[1]) << 16);
    uv.w = bf16rn(v1[2]) | ((uint32_t)bf16rn(v1[3]) << 16);
    vf[(vd >> 4) * 64 + (vd & 15) + 16 * vkq] = uv;
  } else {
    // ---- tab2 (R15-verbatim): f16 score table via MFMA (hi/lo E and Q) ----
    const int bid = blockIdx.x - 10240;
    const int lane = tid & 63;
    const int w = tid >> 6;
    const int qr = lane & 15;
    const int g = lane >> 4;
    const int qt = bid & 31;
    const int h = (bid >> 5) & 15;
    const int b = bid >> 9;
    const int q0 = qt * 64 + w * 16;

    short8v eh[2][2], el[2][2];
#pragma unroll
    for (int rt = 0; rt < 2; ++rt)
#pragma unroll
      for (int dm = 0; dm < 2; ++dm) {
        const float* ep = Eg + (((size_t)(rt * 16 + qr) * Hn + h) * Dn) + dm * 32 + 4 * g;
        const float4 x0 = *reinterpret_cast<const float4*>(ep);
        const float4 x1 = *reinterpret_cast<const float4*>(ep + 16);
        const float xs[8] = {x0.x * LOG2E_8, x0.y * LOG2E_8, x0.z * LOG2E_8, x0.w * LOG2E_8,
                             x1.x * LOG2E_8, x1.y * LOG2E_8, x1.z * LOG2E_8, x1.w * LOG2E_8};
#pragma unroll
        for (int j = 0; j < 8; ++j) {
          const uint16_t hi = bf16rn(xs[j]);
          eh[rt][dm][j] = (short)hi;
          el[rt][dm][j] = (short)bf16rn(xs[j] - bf16f(hi));
        }
      }
    short8v qh[2], ql[2];
#pragma unroll
    for (int dm = 0; dm < 2; ++dm) {
      const float* qp = Qg + (((size_t)b * Qn + q0 + qr) * Hn + h) * Dn + dm * 32 + 4 * g;
      const float4 x0 = *reinterpret_cast<const float4*>(qp);
      const float4 x1 = *reinterpret_cast<const float4*>(qp + 16);
      const float xs[8] = {x0.x, x0.y, x0.z, x0.w, x1.x, x1.y, x1.z, x1.w};
#pragma unroll
      for (int j = 0; j < 8; ++j) {
        const uint16_t hi = bf16rn(xs[j]);
        qh[dm][j] = (short)hi;
        ql[dm][j] = (short)bf16rn(xs[j] - bf16f(hi));
      }
    }
#pragma unroll
    for (int rt = 0; rt < 2; ++rt) {
      f32x4 d;
#pragma unroll
      for (int j = 0; j < 4; ++j)
        d[j] = LOG2E_8 * biasg[(rt * 16 + 4 * g + j) * Hn + h];
#pragma unroll
      for (int dm = 0; dm < 2; ++dm) {
        d = __builtin_amdgcn_mfma_f32_16x16x32_bf16(eh[rt][dm], qh[dm], d, 0, 0, 0);
        d = __builtin_amdgcn_mfma_f32_16x16x32_bf16(el[rt][dm], qh[dm], d, 0, 0, 0);
        d = __builtin_amdgcn_mfma_f32_16x16x32_bf16(eh[rt][dm], ql[dm], d, 0, 0, 0);
      }
      const size_t rowo = ((size_t)(b * 16 + h) * 2048 + q0 + qr) * 64;
      union { ushort4 u4; __half hh[4]; } um, uu;
#pragma unroll
      for (int j = 0; j < 4; ++j) {
        um.hh[j] = __float2half(d[j] + MASK_NEG);
        uu.hh[j] = __float2half(d[j]);
      }
      *reinterpret_cast<ushort4*>(&tabg[rowo + rt * 16 + 4 * g]) = um.u4;
      *reinterpret_cast<ushort4*>(&tabg[rowo + 32 + rt * 16 + 4 * g]) = uu.u4;
    }
  }
}

// ---------------- attn9 (R15 structure + byte-offset gather + fma_mix add) ---------------
// Waves 0-3: keys [0,1024); waves 4-7: keys [1024,2048). Same 128-q tile.
__global__ __launch_bounds__(512, 4) void attn9_kernel(
    const float* __restrict__ Qg, const uint8_t* __restrict__ packed,
    const uint8_t* __restrict__ kfragp, const __half* __restrict__ tabg,
    float* __restrict__ outg) {
  // LDS (disjoint): [0,16384) tab f16[128][64]
  //   [16384,40960)  half0: 3 bufs x 8192 ; [40960,65536) half1: 3 bufs x 8192
  // Epilogue reuse: acc1 f32[128][64] at [16384,49152); l1 f32[128] at [0,512)
  __shared__ alignas(16) char smem[65536];
  const int tid = threadIdx.x;
  const int lane = tid & 63;
  const int w = tid >> 6;     // 0..7
  const int w4 = w & 3;
  const int ks = w >> 2;
  const int qr = lane & 15;
  const int g = lane >> 4;

  // XCD-aware swizzle (512 blocks = 8 XCDs x 64)
  const int wi = (blockIdx.x & 7) * 64 + (blockIdx.x >> 3);
  const int qt = wi & 15;
  const int h = (wi >> 4) & 15;
  const int b = wi >> 8;
  const int q0 = qt * 128;

  char* const myhalf = smem + 16384 + ks * 24576;
  char* bA = myhalf;           // chunk c   (read)
  char* bB = myhalf + 8192;    // chunk c+1 (staged, landing)
  char* bC = myhalf + 16384;   // chunk c+2 (stage target)

  // ---- packed-byte row bases (byte-offset format); tab row base in BYTES ----
  int64_t prow[2];
  int trowB[2];
#pragma unroll
  for (int t = 0; t < 2; ++t) {
    prow[t] = ((int64_t)(b * Qn + q0 + w4 * 32 + t * 16 + qr)) * Kn + ks * 1024 + 4 * g;
    trowB[t] = (w4 * 32 + t * 16 + qr) * 128;   // 64 f16 = 128 B per row
  }
  uint32_t pc[2][2], pn[2][2] = {{0u, 0u}, {0u, 0u}};
#pragma unroll
  for (int t = 0; t < 2; ++t)
#pragma unroll
    for (int st = 0; st < 2; ++st)
      pc[t][st] = *reinterpret_cast<const uint32_t*>(packed + prow[t] + st * 16);

  // ---- entry staging: tab tile (16 KB linear) + chunks 0,1 of my half ----
  {
    const uint8_t* tsrc = reinterpret_cast<const uint8_t*>(
        tabg + ((size_t)(b * 16 + h) * 2048 + q0) * 64);
    char* ld = smem + w * 2048;
    gl_lds16(tsrc + (size_t)w * 2048 + (size_t)lane * 16, ld);
    gl_lds16(tsrc + (size_t)w * 2048 + 1024 + (size_t)lane * 16, ld + 1024);
  }
  const uint8_t* sbase = kfragp + (size_t)(b * 16 + h) * 524288u +
                         (size_t)(ks * 32) * 8192u + (size_t)w4 * 2048 + (size_t)lane * 16;
  {
    char* ld0 = bA + w4 * 2048;
    gl_lds16(sbase, ld0);
    gl_lds16(sbase + 1024, ld0 + 1024);
    char* ld1 = bB + w4 * 2048;
    gl_lds16(sbase + 8192, ld1);
    gl_lds16(sbase + 8192 + 1024, ld1 + 1024);
  }

  // ---- Q fragments direct from global (bf16 via cvtpk; R8-verified mapping) ----
  short8v qhi[2][2];
#pragma unroll
  for (int t = 0; t < 2; ++t)
#pragma unroll
    for (int dm = 0; dm < 2; ++dm) {
      const float* qp = Qg + (((size_t)b * Qn + q0 + w4 * 32 + t * 16 + qr) * Hn + h) * Dn +
                        dm * 32 + 4 * g;
      const float4 x0 = *reinterpret_cast<const float4*>(qp);
      const float4 x1 = *reinterpret_cast<const float4*>(qp + 16);
      u32x4 u;
      u[0] = cvtpk(x0.x, x0.y); u[1] = cvtpk(x0.z, x0.w);
      u[2] = cvtpk(x1.x, x1.y); u[3] = cvtpk(x1.z, x1.w);
      qhi[t][dm] = __builtin_bit_cast(short8v, u);
    }

  asm volatile("s_waitcnt vmcnt(0)" ::: "memory");
  __builtin_amdgcn_sched_barrier(0);
  __syncthreads();

  const short8v ones = {(short)0x3F80, (short)0x3F80, (short)0x3F80, (short)0x3F80,
                        (short)0x3F80, (short)0x3F80, (short)0x3F80, (short)0x3F80};
  const uint8_t* tabB = reinterpret_cast<const uint8_t*>(smem);

  f32x4 acc[2][4] = {{{0.f,0.f,0.f,0.f},{0.f,0.f,0.f,0.f},{0.f,0.f,0.f,0.f},{0.f,0.f,0.f,0.f}},
                     {{0.f,0.f,0.f,0.f},{0.f,0.f,0.f,0.f},{0.f,0.f,0.f,0.f},{0.f,0.f,0.f,0.f}}};
  f32x4 accl[2] = {{0.f,0.f,0.f,0.f},{0.f,0.f,0.f,0.f}};

  for (int c = 0; c < 32; ++c) {
    // (1) issue next packed bytes (older than the gl_lds below)
    if (c + 1 < 32) {
      const int64_t kb = (int64_t)(c + 1) * 32;
#pragma unroll
      for (int t = 0; t < 2; ++t)
#pragma unroll
        for (int st = 0; st < 2; ++st)
          pn[t][st] = *reinterpret_cast<const uint32_t*>(packed + prow[t] + kb + st * 16);
    }
    // (2) issue stage of chunk c+2 (stays in flight across the barrier)
    if (c + 2 < 32) {
      const uint8_t* gs = sbase + (size_t)(c + 2) * 8192u;
      char* ld = bC + w4 * 2048;
      gl_lds16(gs, ld);
      gl_lds16(gs + 1024, ld + 1024);
    }

    // ---- QK^T (swapped, single bf16 pre-scaled) on chunk c ----
    const short8v* kfs = reinterpret_cast<const short8v*>(bA);
    f32x4 s[2][2] = {{{0.f,0.f,0.f,0.f},{0.f,0.f,0.f,0.f}},
                     {{0.f,0.f,0.f,0.f},{0.f,0.f,0.f,0.f}}};
    __builtin_amdgcn_s_setprio(1);
#pragma unroll
    for (int dm = 0; dm < 2; ++dm) {
      const short8v k0 = kfs[dm * 64 + lane];
      const short8v k1 = kfs[(2 + dm) * 64 + lane];
#pragma unroll
      for (int t = 0; t < 2; ++t) {
        s[t][0] = __builtin_amdgcn_mfma_f32_16x16x32_bf16(k0, qhi[t][dm], s[t][0], 0, 0, 0);
        s[t][1] = __builtin_amdgcn_mfma_f32_16x16x32_bf16(k1, qhi[t][dm], s[t][1], 0, 0, 0);
      }
    }
    __builtin_amdgcn_s_setprio(0);

    // V fragments
    const short8v* vfs = reinterpret_cast<const short8v*>(bA + 4096);
    short8v vv[4];
#pragma unroll
    for (int dt = 0; dt < 4; ++dt) vv[dt] = vfs[dt * 64 + lane];

    // ---- per-tile: byte-offset gather + fma_mix add + raw exp2 + PV + ones-MFMA ----
#pragma unroll
    for (int t = 0; t < 2; ++t) {
      float pv[8];
#pragma unroll
      for (int i = 0; i < 8; ++i) {
        const int st = i >> 2, r = i & 3;
        const uint32_t v = (pc[t][st] >> (8 * r)) & 0x7fu;  // byte offset into tab row
        const uint32_t hv =
            *reinterpret_cast<const uint16_t*>(tabB + trowB[t] + (int)v);
        pv[i] = exp2a(addh(hv, s[t][st][r]));
      }
      u32x4 pu;
      pu[0] = cvtpk(pv[0], pv[1]); pu[1] = cvtpk(pv[2], pv[3]);
      pu[2] = cvtpk(pv[4], pv[5]); pu[3] = cvtpk(pv[6], pv[7]);
      const short8v pa = __builtin_bit_cast(short8v, pu);
      __builtin_amdgcn_s_setprio(1);
#pragma unroll
      for (int dt = 0; dt < 4; ++dt)
        acc[t][dt] = __builtin_amdgcn_mfma_f32_16x16x32_bf16(pa, vv[dt], acc[t][dt], 0, 0, 0);
      accl[t] = __builtin_amdgcn_mfma_f32_16x16x32_bf16(pa, ones, accl[t], 0, 0, 0);
      __builtin_amdgcn_s_setprio(0);
    }

    // (3) pc <- pn: compiler wait retires pn AND the older chunk-(c+1) gl_lds
    if (c + 1 < 32) {
#pragma unroll
      for (int t = 0; t < 2; ++t) { pc[t][0] = pn[t][0]; pc[t][1] = pn[t][1]; }
    }

    // (4) guarantee chunk c+1 staged; keep the 6 newest in flight
    if (c < 30) {
      asm volatile("s_waitcnt vmcnt(6)" ::: "memory");
    } else {
      asm volatile("s_waitcnt vmcnt(0)" ::: "memory");
    }
    __builtin_amdgcn_sched_barrier(0);
    __syncthreads();
    char* tmp = bA; bA = bB; bB = bC; bC = tmp;
  }

  // ---- epilogue: in-block merge (ks=1 partials -> LDS; ks=0 combines + stores) ----
  float* const acc1s = reinterpret_cast<float*>(smem + 16384);  // [128][64]
  float* const l1s   = reinterpret_cast<float*>(smem);          // [128]
  if (ks == 1) {
#pragma unroll
    for (int t = 0; t < 2; ++t) {
#pragma unroll
      for (int dt = 0; dt < 4; ++dt)
#pragma unroll
        for (int r = 0; r < 4; ++r)
          acc1s[(w4 * 32 + t * 16 + 4 * g + r) * 64 + dt * 16 + qr] = acc[t][dt][r];
#pragma unroll
      for (int r = 0; r < 4; ++r)
        l1s[w4 * 32 + t * 16 + 4 * g + r] = accl[t][r];  // same value across qr lanes
    }
  }
  __syncthreads();
  if (ks == 0) {
#pragma unroll
    for (int t = 0; t < 2; ++t) {
      const f32x4 l1v = *reinterpret_cast<const f32x4*>(&l1s[w4 * 32 + t * 16 + 4 * g]);
      f32x4 linv;
#pragma unroll
      for (int r = 0; r < 4; ++r) linv[r] = 1.0f / (accl[t][r] + l1v[r]);
#pragma unroll
      for (int dt = 0; dt < 4; ++dt)
#pragma unroll
        for (int r = 0; r < 4; ++r) {
          const int lrow = w4 * 32 + t * 16 + 4 * g + r;
          const float o = (acc[t][dt][r] + acc1s[lrow * 64 + dt * 16 + qr]) * linv[r];
          outg[(((size_t)b * Qn + q0 + lrow) * Hn + h) * Dn + dt * 16 + qr] = o;
        }
    }
  }
}

// ---------------- fallback (ws too small): fully self-contained, no scratch ----------------
__global__ __launch_bounds__(256) void attn_old_kernel(
    const float* __restrict__ Qg, const float* __restrict__ Kg,
    const float* __restrict__ Vg, const int* __restrict__ maskg,
    const int* __restrict__ idsg, const float* __restrict__ Eg,
    const float* __restrict__ biasg, float* __restrict__ outg) {
  __shared__ alignas(16) char smem[34304];
  float* const allrel = reinterpret_cast<float*>(smem);
  float* const q_lds  = reinterpret_cast<float*>(smem + 8448);
  float* const et_lds = reinterpret_cast<float*>(smem + 25856);
  uint4* const kfrag  = reinterpret_cast<uint4*>(smem + 8448);
  uint4* const vfrag  = reinterpret_cast<uint4*>(smem + 16640);

  const int tid  = threadIdx.x;
  const int lane = tid & 63;
  const int w    = tid >> 6;
  const int qr   = lane & 15;
  const int g    = lane >> 4;

  const int bid = blockIdx.x;
  const int h  = bid & 15;
  const int qt = (bid >> 4) & 31;
  const int b  = bid >> 9;
  const int q0 = qt * 64;

  {
    const int row = tid >> 2, dq = (tid & 3) * 16;
    const float4* s4 =
        reinterpret_cast<const float4*>(Qg + (((b * Qn) + q0 + row) * Hn + h) * Dn + dq);
    float4* dst = reinterpret_cast<float4*>(&q_lds[row * 68 + dq]);
#pragma unroll
    for (int i = 0; i < 4; ++i) dst[i] = s4[i];
  }
  {
    const int r = tid >> 3, d0 = (tid & 7) * 8;
    const float* src = Eg + ((r * Hn + h) * Dn + d0);
#pragma unroll
    for (int i = 0; i < 8; ++i) et_lds[(d0 + i) * 33 + r] = src[i];
  }
  __syncthreads();

  const int qloc = w * 16 + qr;
  short8v qhi[2], qlo[2];
#pragma unroll
  for (int dm = 0; dm < 2; ++dm) {
#pragma unroll
    for (int j = 0; j < 8; ++j) {
      const int dl = (j < 4) ? (4 * g + j) : (16 + 4 * g + (j - 4));
      const float x = q_lds[qloc * 68 + dm * 32 + dl];
      const uint16_t hi = bf16rn(x);
      qhi[dm][j] = (short)hi;
      qlo[dm][j] = (short)bf16rn(x - bf16f(hi));
    }
  }

  {
    const int r = tid & 31, q8 = tid >> 5;
    float acc[8] = {0.f, 0.f, 0.f, 0.f, 0.f, 0.f, 0.f, 0.f};
    const float bias = biasg[r * Hn + h];
    for (int d = 0; d < 64; ++d) {
      const float e = et_lds[d * 33 + r];
#pragma unroll
      for (int i = 0; i < 8; ++i) acc[i] += e * q_lds[(q8 * 8 + i) * 68 + d];
    }
#pragma unroll
    for (int i = 0; i < 8; ++i)
      allrel[(q8 * 8 + i) * 33 + r] = 0.125f * (acc[i] + bias);
  }
  __syncthreads();

  const int sdq = tid & 7, srow = (tid >> 3) & 15, stile = tid >> 7;
  const int sg = sdq & 3, sdm = sdq >> 2;
  int koff = (((b * Kn) + stile * 16 + srow) * Hn + h) * Dn + (sdm * 32 + sg * 4);
  const int kslotH = (stile * 2 + sdm) * 64 + (srow + 16 * sg);
  const int kslotL = (4 + stile * 2 + sdm) * 64 + (srow + 16 * sg);
  const int vd = tid & 63, vkq = tid >> 6;
  int voff = (((b * Kn) + vkq * 4) * Hn + h) * Dn + vd;
  const int vslot = (vd >> 4) * 64 + (vd & 15) + 16 * vkq;

  const int qglob = q0 + qloc;
  const int prow = (b * Qn + qglob) * Kn + 4 * g;

  f32x4 acc[4] = {{0.f,0.f,0.f,0.f},{0.f,0.f,0.f,0.f},{0.f,0.f,0.f,0.f},{0.f,0.f,0.f,0.f}};
  float mrun = -1e30f, lrun = 0.f;

  const short8v* kfs = reinterpret_cast<const short8v*>(kfrag);
  const short8v* vfs = reinterpret_cast<const short8v*>(vfrag);

  for (int c = 0; c < 64; ++c) {
    const int kb = c * 32;
    __syncthreads();
    {
      const float4 x0 = *reinterpret_cast<const float4*>(Kg + koff);
      const float4 x1 = *reinterpret_cast<const float4*>(Kg + koff + 16);
      koff += 32 * Hn * Dn;
      const float xs0[4] = {x0.x, x0.y, x0.z, x0.w};
      const float xs1[4] = {x1.x, x1.y, x1.z, x1.w};
      uint16_t hh[8], ll[8];
#pragma unroll
      for (int i = 0; i < 4; ++i) {
        const uint16_t h0 = bf16rn(xs0[i]);
        const uint16_t h1 = bf16rn(xs1[i]);
        hh[i] = h0; hh[4 + i] = h1;
        ll[i] = bf16rn(xs0[i] - bf16f(h0));
        ll[4 + i] = bf16rn(xs1[i] - bf16f(h1));
      }
      uint4 uh, ul;
      uh.x = hh[0] | ((uint32_t)hh[1] << 16); uh.y = hh[2] | ((uint32_t)hh[3] << 16);
      uh.z = hh[4] | ((uint32_t)hh[5] << 16); uh.w = hh[6] | ((uint32_t)hh[7] << 16);
      ul.x = ll[0] | ((uint32_t)ll[1] << 16); ul.y = ll[2] | ((uint32_t)ll[3] << 16);
      ul.z = ll[4] | ((uint32_t)ll[5] << 16); ul.w = ll[6] | ((uint32_t)ll[7] << 16);
      kfrag[kslotH] = uh;
      kfrag[kslotL] = ul;
    }
    {
      float v0[4], v1[4];
#pragma unroll
      for (int i = 0; i < 4; ++i) {
        v0[i] = Vg[voff + i * (Hn * Dn)];
        v1[i] = Vg[voff + 16 * Hn * Dn + i * (Hn * Dn)];
      }
      voff += 32 * Hn * Dn;
      uint4 uv;
      uv.x = bf16rn(v0[0]) | ((uint32_t)bf16rn(v0[1]) << 16);
      uv.y = bf16rn(v0[2]) | ((uint32_t)bf16rn(v0[3]) << 16);
      uv.z = bf16rn(v1[0]) | ((uint32_t)bf16rn(v1[1]) << 16);
      uv.w = bf16rn(v1[2]) | ((uint32_t)bf16rn(v1[3]) << 16);
      vfrag[vslot] = uv;
    }
    __syncthreads();

    f32x4 s0 = {0.f, 0.f, 0.f, 0.f}, s1 = {0.f, 0.f, 0.f, 0.f};
#pragma unroll
    for (int dm = 0; dm < 2; ++dm) {
      const short8v k0h = kfs[(dm) * 64 + lane];
      const short8v k1h = kfs[(2 + dm) * 64 + lane];
      const short8v k0l = kfs[(4 + dm) * 64 + lane];
      const short8v k1l = kfs[(6 + dm) * 64 + lane];
      s0 = __builtin_amdgcn_mfma_f32_16x16x32_bf16(k0h, qhi[dm], s0, 0, 0, 0);
      s1 = __builtin_amdgcn_mfma_f32_16x16x32_bf16(k1h, qhi[dm], s1, 0, 0, 0);
      s0 = __builtin_amdgcn_mfma_f32_16x16x32_bf16(k0h, qlo[dm], s0, 0, 0, 0);
      s1 = __builtin_amdgcn_mfma_f32_16x16x32_bf16(k1h, qlo[dm], s1, 0, 0, 0);
      s0 = __builtin_amdgcn_mfma_f32_16x16x32_bf16(k0l, qhi[dm], s0, 0, 0, 0);
      s1 = __builtin_amdgcn_mfma_f32_16x16x32_bf16(k1l, qhi[dm], s1, 0, 0, 0);
    }

    float sv[8];
    {
      const int ib = prow + kb;
      const int4 i0 = *reinterpret_cast<const int4*>(idsg + ib);
      const int4 i1 = *reinterpret_cast<const int4*>(idsg + ib + 16);
      const int4 m0 = *reinterpret_cast<const int4*>(maskg + ib);
      const int4 m1 = *reinterpret_cast<const int4*>(maskg + ib + 16);
      const int ia0[4] = {i0.x, i0.y, i0.z, i0.w};
      const int ia1[4] = {i1.x, i1.y, i1.z, i1.w};
      const int ma0[4] = {m0.x, m0.y, m0.z, m0.w};
      const int ma1[4] = {m1.x, m1.y, m1.z, m1.w};
#pragma unroll
      for (int r = 0; r < 4; ++r) {
        sv[r]     = 0.125f * s0[r] + allrel[qloc * 33 + ia0[r]] + (ma0[r] ? 0.f : -10000.f);
        sv[4 + r] = 0.125f * s1[r] + allrel[qloc * 33 + ia1[r]] + (ma1[r] ? 0.f : -10000.f);
      }
    }

    float m8 = sv[0];
#pragma unroll
    for (int i = 1; i < 8; ++i) m8 = fmaxf(m8, sv[i]);
    m8 = fmaxf(m8, __shfl_xor(m8, 16));
    m8 = fmaxf(m8, __shfl_xor(m8, 32));
    const float mnew = fmaxf(mrun, m8);
    const float sc = __expf(mrun - mnew);
    mrun = mnew;
    float pv[8];
    float ps = 0.f;
#pragma unroll
    for (int i = 0; i < 8; ++i) { pv[i] = __expf(sv[i] - mnew); ps += pv[i]; }
    ps += __shfl_xor(ps, 16);
    ps += __shfl_xor(ps, 32);
    lrun = lrun * sc + ps;

    f32x4 scv;
#pragma unroll
    for (int r = 0; r < 4; ++r) scv[r] = __shfl(sc, 4 * g + r);
#pragma unroll
    for (int dt = 0; dt < 4; ++dt) acc[dt] *= scv;

    short8v pa;
#pragma unroll
    for (int i = 0; i < 8; ++i) pa[i] = (short)bf16rn(pv[i]);
#pragma unroll
    for (int dt = 0; dt < 4; ++dt)
      acc[dt] = __builtin_amdgcn_mfma_f32_16x16x32_bf16(pa, vfs[dt * 64 + lane], acc[dt], 0, 0, 0);
  }

  const float linv = 1.0f / lrun;
  f32x4 lv;
#pragma unroll
  for (int r = 0; r < 4; ++r) lv[r] = __shfl(linv, 4 * g + r);
#pragma unroll
  for (int dt = 0; dt < 4; ++dt) {
#pragma unroll
    for (int r = 0; r < 4; ++r) {
      const int qrow = q0 + w * 16 + 4 * g + r;
      outg[(((b * Qn) + qrow) * Hn + h) * Dn + dt * 16 + qr] = acc[dt][r] * lv[r];
    }
  }
}

extern "C" void kernel_launch(void* const* d_in, const int* in_sizes, int n_in,
                              void* d_out, int out_size, void* d_ws, size_t ws_size,
                              hipStream_t stream) {
  const float* Qg    = (const float*)d_in[0];
  const float* Kg    = (const float*)d_in[1];
  const float* Vg    = (const float*)d_in[2];
  const int*   maskg = (const int*)d_in[3];
  const int*   idsg  = (const int*)d_in[4];
  const float* Eg    = (const float*)d_in[5];
  const float* biasg = (const float*)d_in[6];
  float* outg = (float*)d_out;

  // ws layout
  const size_t oPack = 0;                 // 8,388,608
  const size_t oK    = 8388608;           // +16,777,216 -> 25,165,824
  const size_t oT    = 25165824;          // +8,388,608  -> 33,554,432
  const size_t need = 33554432;

  uint8_t* ws = (uint8_t*)d_ws;

  if (ws_size >= need) {
    // fused prepass: 8192 (pack) + 2048 (kfrag) + 1024 (tab2) = 11264 blocks
    prep_kernel<<<11264, 256, 0, stream>>>(
        idsg, maskg, Kg, Vg, Qg, Eg, biasg,
        (uint32_t*)(ws + oPack), ws + oK, (__half*)(ws + oT));
    attn9_kernel<<<Bn * Hn * (Qn / 128), 512, 0, stream>>>(
        Qg, ws + oPack, ws + oK, (const __half*)(ws + oT), outg);
  } else {
    attn_old_kernel<<<Bn * Hn * (Qn / 64), 256, 0, stream>>>(
        Qg, Kg, Vg, maskg, idsg, Eg, biasg, outg);
  }
}